// Round 4
// baseline (313.563 us; speedup 1.0000x reference)
//
#include <hip/hip_runtime.h>

#define B_   2
#define CIN  16
#define HIN  384
#define WIN  1280
#define CO   24
#define HQ   96
#define WL   320
#define WR   1280
#define DMAX 64

__device__ __forceinline__ float lk(float v) { return v >= 0.f ? v : 0.2f * v; }

// ============ Kernel A: em_left (4x4 s4,4 VALID) + leaky + rc 1x1 + leaky ====
// block 256 = 128 px * 2 o-halves (12 out-ch each); grid 480  [R1 union version]
__global__ __launch_bounds__(256) void k_left(
    const float* __restrict__ x, const float* __restrict__ w_em,
    const float* __restrict__ b_em, const float* __restrict__ w_rc,
    const float* __restrict__ b_rc, float* __restrict__ out)
{
    __shared__ float smem[CO * CIN * 16];  // em weights during conv, then em acts
    __shared__ float swt[CO * CO];         // rc weights transposed [c][o]
    __shared__ float sbe[CO], sbr[CO];

    for (int i = threadIdx.x; i < CO * CIN * 16; i += 256) smem[i] = w_em[i];
    for (int i = threadIdx.x; i < CO * CO; i += 256) swt[i] = w_rc[(i % CO) * CO + (i / CO)];
    if (threadIdx.x < CO) { sbe[threadIdx.x] = b_em[threadIdx.x]; sbr[threadIdx.x] = b_rc[threadIdx.x]; }
    __syncthreads();

    const int t = threadIdx.x;
    const int half = t >> 7, pxl = t & 127;
    const int obase = half * 12;
    const int flat = blockIdx.x * 128 + pxl;       // < 61440
    const int j = flat % WL, h = (flat / WL) % HQ, b = flat / (WL * HQ);

    float acc[12];
#pragma unroll
    for (int oo = 0; oo < 12; ++oo) acc[oo] = sbe[obase + oo];

    for (int c = 0; c < CIN; ++c) {
#pragma unroll
        for (int kh = 0; kh < 4; ++kh) {
            const float4 v = *(const float4*)(x + ((size_t)(b * CIN + c) * HIN + 4 * h + kh) * WIN + 4 * j);
#pragma unroll
            for (int oo = 0; oo < 12; ++oo) {
                const float4 wv = *(const float4*)&smem[(((obase + oo) * CIN + c) * 4 + kh) * 4];
                acc[oo] += v.x * wv.x + v.y * wv.y + v.z * wv.z + v.w * wv.w;
            }
        }
    }
    __syncthreads();
#pragma unroll
    for (int oo = 0; oo < 12; ++oo) smem[(obase + oo) * 128 + pxl] = lk(acc[oo]);
    __syncthreads();

    float acc2[12];
#pragma unroll
    for (int oo = 0; oo < 12; ++oo) acc2[oo] = sbr[obase + oo];
    for (int c = 0; c < CO; ++c) {
        const float in_c = smem[c * 128 + pxl];
#pragma unroll
        for (int oo = 0; oo < 12; ++oo) acc2[oo] += in_c * swt[c * CO + obase + oo];
    }
#pragma unroll
    for (int oo = 0; oo < 12; ++oo)
        out[((size_t)(b * CO + obase + oo) * HQ + h) * WL + j] = lk(acc2[oo]);
}

// ======= Kernel B: em_right (4x4 s4,1 pad 1,2) + leaky + rc 1x1 + leaky ======
// R4 (this round): ROW-PAIRED. Each thread computes its 4-col group for TWO
// rows (h, h+48) of the same tile, so each weight ds_read_b128 serves 768
// FMAs instead of 384 -- conv LDS-pipe demand halves (R0 analysis: LDS pipe
// ~40us and VALU ~41us were each ~50% of the 85us kernel, dependency
// ping-pong). Accumulation rewritten as pure fmaf chains (4 FMA / 4 MACs,
// was mul+3fma+add = 1.25x). Grid 480 = 2b x 48hp x 5tiles; acts [24][2][256]
// unioned with weights (48KB). Edge cols via two aligned dwordx2 + cndmask
// (masks identical for both rows).
__global__ __launch_bounds__(256) void k_right(
    const float* __restrict__ x, const float* __restrict__ w_em,
    const float* __restrict__ b_em, const float* __restrict__ w_rc,
    const float* __restrict__ b_rc, float* __restrict__ out)
{
    __shared__ __align__(16) float buf[CO * 512];  // weights (6144 fl) then acts [24][2][256]
    __shared__ float swt[CO * CO];
    __shared__ float sbe[CO], sbr[CO];

    for (int i = threadIdx.x; i < CO * CIN * 16; i += 256) buf[i] = w_em[i];
    for (int i = threadIdx.x; i < CO * CO; i += 256) swt[i] = w_rc[(i % CO) * CO + (i / CO)];
    if (threadIdx.x < CO) { sbe[threadIdx.x] = b_em[threadIdx.x]; sbr[threadIdx.x] = b_rc[threadIdx.x]; }
    __syncthreads();

    const int t = threadIdx.x;
    const int L = t & 63, quarter = t >> 6;
    const int obase = quarter * 6;
    const int tile = blockIdx.x % 5;
    const int rest = blockIdx.x / 5;
    const int hp = rest % 48, b = rest / 48;
    const int h0 = hp, h1 = hp + 48;
    const int jbase = tile * 256;

    // Edge handling (loop-invariant; same masks for both rows).
    const bool vm1 = (jbase + 4 * L) > 0;
    const bool vp  = (jbase + 4 * L + 4) < WIN;
    const int  om1 = vm1 ? (4 * L - 2) : 0;
    const int  op4 = vp  ? (4 * L + 4) : 0;
    const int  L4  = 4 * L;
    const size_t cstride = (size_t)HIN * WIN;

    const float* xc0 = x + ((size_t)(b * CIN) * HIN + 4 * h0) * WIN + jbase;
    const float* xc1 = xc0 + (size_t)4 * 48 * WIN;   // row h1 of same channel

    float acc[2][4][6];
#pragma unroll
    for (int oo = 0; oo < 6; ++oo) {
        const float be = sbe[obase + oo];
#pragma unroll
        for (int k = 0; k < 4; ++k) { acc[0][k][oo] = be; acc[1][k][oo] = be; }
    }

    for (int c = 0; c < CIN; ++c) {
        const float* r0 = xc0 + c * cstride;
        const float* r1 = xc1 + c * cstride;
#pragma unroll
        for (int kh = 0; kh < 4; ++kh) {
            const float* p0 = r0 + kh * WIN;
            const float* p1 = r1 + kh * WIN;
            const float4 v0 = *(const float4*)(p0 + L4);
            const float2 A0 = *(const float2*)(p0 + om1);
            const float2 C0 = *(const float2*)(p0 + op4);
            const float4 v1 = *(const float4*)(p1 + L4);
            const float2 A1 = *(const float2*)(p1 + om1);
            const float2 C1 = *(const float2*)(p1 + op4);
            float in0[7], in1[7];
            in0[0] = vm1 ? A0.y : 0.f;
            in0[1] = v0.x; in0[2] = v0.y; in0[3] = v0.z; in0[4] = v0.w;
            in0[5] = vp ? C0.x : 0.f;
            in0[6] = vp ? C0.y : 0.f;
            in1[0] = vm1 ? A1.y : 0.f;
            in1[1] = v1.x; in1[2] = v1.y; in1[3] = v1.z; in1[4] = v1.w;
            in1[5] = vp ? C1.x : 0.f;
            in1[6] = vp ? C1.y : 0.f;
#pragma unroll
            for (int oo = 0; oo < 6; ++oo) {
                const float4 wv = *(const float4*)&buf[(((obase + oo) * CIN + c) * 4 + kh) * 4];
#pragma unroll
                for (int k = 0; k < 4; ++k) {
                    float a0 = acc[0][k][oo];
                    a0 = fmaf(in0[k], wv.x, a0);
                    a0 = fmaf(in0[k + 1], wv.y, a0);
                    a0 = fmaf(in0[k + 2], wv.z, a0);
                    a0 = fmaf(in0[k + 3], wv.w, a0);
                    acc[0][k][oo] = a0;
                    float a1 = acc[1][k][oo];
                    a1 = fmaf(in1[k], wv.x, a1);
                    a1 = fmaf(in1[k + 1], wv.y, a1);
                    a1 = fmaf(in1[k + 2], wv.z, a1);
                    a1 = fmaf(in1[k + 3], wv.w, a1);
                    acc[1][k][oo] = a1;
                }
            }
        }
    }
    __syncthreads();   // all waves done reading em weights; buf becomes act buffer
#pragma unroll
    for (int oo = 0; oo < 6; ++oo) {
        float4 s0 = make_float4(lk(acc[0][0][oo]), lk(acc[0][1][oo]), lk(acc[0][2][oo]), lk(acc[0][3][oo]));
        float4 s1 = make_float4(lk(acc[1][0][oo]), lk(acc[1][1][oo]), lk(acc[1][2][oo]), lk(acc[1][3][oo]));
        *(float4*)&buf[((obase + oo) * 2 + 0) * 256 + 4 * L] = s0;
        *(float4*)&buf[((obase + oo) * 2 + 1) * 256 + 4 * L] = s1;
    }
    __syncthreads();

#pragma unroll 1
    for (int g = 0; g < 2; ++g) {
        float acc2[CO];
#pragma unroll
        for (int o = 0; o < CO; ++o) acc2[o] = sbr[o];
        for (int c = 0; c < CO; ++c) {
            const float in_c = buf[(c * 2 + g) * 256 + t];
#pragma unroll
            for (int o = 0; o < CO; ++o) acc2[o] = fmaf(in_c, swt[c * CO + o], acc2[o]);
        }
        const int hg = g ? h1 : h0;
#pragma unroll
        for (int o = 0; o < CO; ++o)
            out[((size_t)(b * CO + o) * HQ + hg) * WR + jbase + t] = lk(acc2[o]);
    }
}

// ====== Kernel C: cost volume + min/argmin + tf 1x1 + output assembly ========
// block 256 = 64 j-lanes x 4 waves (wave w owns d in [16w,16w+16)); grid 960.
// LDS layout: frs[c*324 + 2 + (col - colbase)], colbase = 4*j0-64; cols<0
// replicated with fr[c][0] (reference's lower clip; upper clip never fires).
// The +2 shift makes each (c, d-quad) gather group of 4 consecutive cols
// 16B-aligned -> one ds_read_b128 replaces 4 ds_read_b32. Channel-ascending
// += of fabsf keeps costs bitwise-identical -> argmin tie behavior preserved.
__global__ __launch_bounds__(256) void k_cost(
    const float* __restrict__ fl, const float* __restrict__ fr,
    const float* __restrict__ wtf, const float* __restrict__ btf,
    float* __restrict__ out, float* __restrict__ cost)
{
    __shared__ float frs[CO * 324];       // 31104 B
    __shared__ float sbest[256];
    __shared__ int   sbd[256];

    const int t  = threadIdx.x;
    const int j  = t & 63;                 // lane = local col
    const int w  = t >> 6;                 // wave: d in [16w, 16w+16)
    const int jc = blockIdx.x % 5;
    const int r  = blockIdx.x / 5;
    const int h  = r % HQ, b = r / HQ;
    const int j0 = jc * 64;
    const int jg = j0 + j;
    const int colbase = 4 * j0 - 64;

    // stage 24 rows x 320 cols (coalesced; left-clip replication)
    for (int idx = t; idx < CO * 320; idx += 256) {
        const int c = idx / 320, Wd = idx % 320;
        const int col = colbase + Wd;
        frs[c * 324 + 2 + Wd] = fr[((size_t)(b * CO + c) * HQ + h) * WR + (col > 0 ? col : 0)];
    }
    __syncthreads();

    float acc[4][4];                       // [q][r], d = 16w + 4q + r
#pragma unroll
    for (int q = 0; q < 4; ++q)
#pragma unroll
        for (int rr = 0; rr < 4; ++rr) acc[q][rr] = 0.f;

    for (int c = 0; c < CO; ++c) {
        const float flc = fl[((size_t)(b * CO + c) * HQ + h) * WL + jg];
        const float* base = &frs[c * 324 + 4 * j + 64];
#pragma unroll
        for (int q = 0; q < 4; ++q) {
            const int D = 4 * w + q;
            const float4 v = *(const float4*)(base - 4 * D);  // 16B-aligned
            acc[q][0] += fabsf(flc - v.w);   // d = 4D
            acc[q][1] += fabsf(flc - v.z);   // d = 4D+1
            acc[q][2] += fabsf(flc - v.y);   // d = 4D+2
            acc[q][3] += fabsf(flc - v.x);   // d = 4D+3
        }
    }

    // cost volume writes (coalesced over jg)
#pragma unroll
    for (int q = 0; q < 4; ++q)
#pragma unroll
        for (int rr = 0; rr < 4; ++rr) {
            const int d = 16 * w + 4 * q + rr;
            cost[((size_t)(b * DMAX + d) * HQ + h) * WL + jg] = acc[q][rr];
        }

    // per-thread min / first-occurrence argmin (ascending d within wave range)
    float best = acc[0][0]; int bd = 16 * w;
#pragma unroll
    for (int q = 0; q < 4; ++q)
#pragma unroll
        for (int rr = 0; rr < 4; ++rr) {
            if (q == 0 && rr == 0) continue;
            const int d = 16 * w + 4 * q + rr;
            if (acc[q][rr] < best) { best = acc[q][rr]; bd = d; }
        }
    sbest[t] = best; sbd[t] = bd;
    __syncthreads();

    if (t < 64) {
        float cur = sbest[j]; int curd = sbd[j];
#pragma unroll
        for (int g = 1; g < 4; ++g) {
            const float v = sbest[g * 64 + j];
            if (v < cur) { cur = v; curd = sbd[g * 64 + j]; }
        }
        float flr[CO];
#pragma unroll
        for (int c = 0; c < CO; ++c) flr[c] = fl[((size_t)(b * CO + c) * HQ + h) * WL + jg];
#pragma unroll
        for (int o = 0; o < 13; ++o) {
            float a = btf[o] + wtf[o * 25] * cur;
#pragma unroll
            for (int c = 0; c < CO; ++c) a += wtf[o * 25 + 1 + c] * flr[c];
            out[((size_t)(b * 16 + 3 + o) * HQ + h) * WL + jg] = lk(a);
        }
        out[((size_t)(b * 16 + 0) * HQ + h) * WL + jg] = (float)curd;
        out[((size_t)(b * 16 + 1) * HQ + h) * WL + jg] = 0.f;
        out[((size_t)(b * 16 + 2) * HQ + h) * WL + jg] = 0.f;
    }
}

extern "C" void kernel_launch(void* const* d_in, const int* in_sizes, int n_in,
                              void* d_out, int out_size, void* d_ws, size_t ws_size,
                              hipStream_t stream) {
    const float* fl_in = (const float*)d_in[0];
    const float* fr_in = (const float*)d_in[1];
    // d_in[2] = max_disp (int) -- fixed 64
    const float* w_em = (const float*)d_in[3];
    const float* b_em = (const float*)d_in[4];
    const float* w_rc = (const float*)d_in[5];
    const float* b_rc = (const float*)d_in[6];
    const float* w_tf = (const float*)d_in[7];
    const float* b_tf = (const float*)d_in[8];

    float* out  = (float*)d_out;
    float* cost = out + (size_t)B_ * 16 * HQ * WL;

    float* fl_ws = (float*)d_ws;                               // [2,24,96,320]
    float* fr_ws = fl_ws + (size_t)B_ * CO * HQ * WL;          // [2,24,96,1280]

    hipLaunchKernelGGL(k_right, dim3(480), dim3(256), 0, stream,
                       fr_in, w_em, b_em, w_rc, b_rc, fr_ws);
    hipLaunchKernelGGL(k_left,  dim3(480), dim3(256), 0, stream,
                       fl_in, w_em, b_em, w_rc, b_rc, fl_ws);
    hipLaunchKernelGGL(k_cost,  dim3(960), dim3(256), 0, stream,
                       fl_ws, fr_ws, w_tf, b_tf, out, cost);
}

// Round 5
// 252.070 us; speedup vs baseline: 1.2440x; 1.2440x over previous
//
#include <hip/hip_runtime.h>

#define B_   2
#define CIN  16
#define HIN  384
#define WIN  1280
#define CO   24
#define HQ   96
#define WL   320
#define WR   1280
#define DMAX 64

__device__ __forceinline__ float lk(float v) { return v >= 0.f ? v : 0.2f * v; }

// ============ Kernel A: em_left (4x4 s4,4 VALID) + leaky + rc 1x1 + leaky ====
// block 256 = 128 px * 2 o-halves (12 out-ch each); grid 480.
// R5: fmaf chains (R4-verified numerics) + float4 swt reads in rc stage
// (576 ds_read_b32 -> 144 ds_read_b128 per thread was the k_right ratio; here
// 288 -> 72). Same values, same add order -> bitwise identical rc outputs.
__global__ __launch_bounds__(256) void k_left(
    const float* __restrict__ x, const float* __restrict__ w_em,
    const float* __restrict__ b_em, const float* __restrict__ w_rc,
    const float* __restrict__ b_rc, float* __restrict__ out)
{
    __shared__ float smem[CO * CIN * 16];  // em weights during conv, then em acts
    __shared__ __align__(16) float swt[CO * CO];   // rc weights transposed [c][o]
    __shared__ float sbe[CO], sbr[CO];

    for (int i = threadIdx.x; i < CO * CIN * 16; i += 256) smem[i] = w_em[i];
    for (int i = threadIdx.x; i < CO * CO; i += 256) swt[i] = w_rc[(i % CO) * CO + (i / CO)];
    if (threadIdx.x < CO) { sbe[threadIdx.x] = b_em[threadIdx.x]; sbr[threadIdx.x] = b_rc[threadIdx.x]; }
    __syncthreads();

    const int t = threadIdx.x;
    const int half = t >> 7, pxl = t & 127;
    const int obase = half * 12;
    const int flat = blockIdx.x * 128 + pxl;       // < 61440
    const int j = flat % WL, h = (flat / WL) % HQ, b = flat / (WL * HQ);

    float acc[12];
#pragma unroll
    for (int oo = 0; oo < 12; ++oo) acc[oo] = sbe[obase + oo];

    for (int c = 0; c < CIN; ++c) {
#pragma unroll
        for (int kh = 0; kh < 4; ++kh) {
            const float4 v = *(const float4*)(x + ((size_t)(b * CIN + c) * HIN + 4 * h + kh) * WIN + 4 * j);
#pragma unroll
            for (int oo = 0; oo < 12; ++oo) {
                const float4 wv = *(const float4*)&smem[(((obase + oo) * CIN + c) * 4 + kh) * 4];
                float a = acc[oo];
                a = fmaf(v.x, wv.x, a);
                a = fmaf(v.y, wv.y, a);
                a = fmaf(v.z, wv.z, a);
                a = fmaf(v.w, wv.w, a);
                acc[oo] = a;
            }
        }
    }
    __syncthreads();
#pragma unroll
    for (int oo = 0; oo < 12; ++oo) smem[(obase + oo) * 128 + pxl] = lk(acc[oo]);
    __syncthreads();

    float acc2[12];
#pragma unroll
    for (int oo = 0; oo < 12; ++oo) acc2[oo] = sbr[obase + oo];
    for (int c = 0; c < CO; ++c) {
        const float in_c = smem[c * 128 + pxl];
#pragma unroll
        for (int m = 0; m < 3; ++m) {
            const float4 wv = *(const float4*)&swt[c * CO + obase + 4 * m];   // 16B aligned
            acc2[4 * m + 0] = fmaf(in_c, wv.x, acc2[4 * m + 0]);
            acc2[4 * m + 1] = fmaf(in_c, wv.y, acc2[4 * m + 1]);
            acc2[4 * m + 2] = fmaf(in_c, wv.z, acc2[4 * m + 2]);
            acc2[4 * m + 3] = fmaf(in_c, wv.w, acc2[4 * m + 3]);
        }
    }
#pragma unroll
    for (int oo = 0; oo < 12; ++oo)
        out[((size_t)(b * CO + obase + oo) * HQ + h) * WL + j] = lk(acc2[oo]);
}

// ======= Kernel B: em_right (4x4 s4,1 pad 1,2) + leaky + rc 1x1 + leaky ======
// R1 structure (single row, 4 px/thread, LDS union 27136B, VGPR ~128 -- the
// proven 85us config; R4's row-pairing spilled at VGPR 256). R5 deltas:
// (a) fmaf chains in conv (5 -> 4 VALU per 4-MAC group; R4-verified safe);
// (b) rc weight reads as float4: swt[c][o..o+3] contiguous & 16B-aligned ->
//     576 ds_read_b32 -> 144 ds_read_b128 per thread (rc LDS-pipe demand was
//     ~21us chip-wide, larger than the conv's weight reads). Bitwise identical.
__global__ __launch_bounds__(256) void k_right(
    const float* __restrict__ x, const float* __restrict__ w_em,
    const float* __restrict__ b_em, const float* __restrict__ w_rc,
    const float* __restrict__ b_rc, float* __restrict__ out)
{
    __shared__ __align__(16) float sw[CO * CIN * 16];  // weights, then em acts [24][256]
    __shared__ __align__(16) float swt[CO * CO];
    __shared__ float sbe[CO], sbr[CO];

    for (int i = threadIdx.x; i < CO * CIN * 16; i += 256) sw[i] = w_em[i];
    for (int i = threadIdx.x; i < CO * CO; i += 256) swt[i] = w_rc[(i % CO) * CO + (i / CO)];
    if (threadIdx.x < CO) { sbe[threadIdx.x] = b_em[threadIdx.x]; sbr[threadIdx.x] = b_rc[threadIdx.x]; }
    __syncthreads();

    const int t = threadIdx.x;
    const int L = t & 63, quarter = t >> 6;
    const int obase = quarter * 6;
    const int row = blockIdx.x / 5, jbase = (blockIdx.x % 5) * 256;
    const int b = row / HQ, h = row % HQ;

    // Edge handling (loop-invariant). Aligned dwordx2 + cndmask (R6: shuffles
    // and guarded loads regress).
    const bool vm1 = (jbase + 4 * L) > 0;
    const bool vp  = (jbase + 4 * L + 4) < WIN;
    const int  om1 = vm1 ? (4 * L - 2) : 0;
    const int  op4 = vp  ? (4 * L + 4) : 0;

    float acc[4][6];
#pragma unroll
    for (int k = 0; k < 4; ++k)
#pragma unroll
        for (int oo = 0; oo < 6; ++oo) acc[k][oo] = sbe[obase + oo];

    for (int c = 0; c < CIN; ++c) {
#pragma unroll
        for (int kh = 0; kh < 4; ++kh) {
            const float* xr = x + ((size_t)(b * CIN + c) * HIN + 4 * h + kh) * WIN + jbase;
            const float4  v = *(const float4*)(xr + 4 * L);
            const float2  A = *(const float2*)(xr + om1);   // cols 4L-2, 4L-1
            const float2  C = *(const float2*)(xr + op4);   // cols 4L+4, 4L+5
            float in[7];
            in[0] = vm1 ? A.y : 0.f;
            in[1] = v.x; in[2] = v.y; in[3] = v.z; in[4] = v.w;
            in[5] = vp ? C.x : 0.f;
            in[6] = vp ? C.y : 0.f;
#pragma unroll
            for (int oo = 0; oo < 6; ++oo) {
                const float4 wv = *(const float4*)&sw[(((obase + oo) * CIN + c) * 4 + kh) * 4];
#pragma unroll
                for (int k = 0; k < 4; ++k) {
                    float a = acc[k][oo];
                    a = fmaf(in[k],     wv.x, a);
                    a = fmaf(in[k + 1], wv.y, a);
                    a = fmaf(in[k + 2], wv.z, a);
                    a = fmaf(in[k + 3], wv.w, a);
                    acc[k][oo] = a;
                }
            }
        }
    }
    __syncthreads();   // all waves done reading em weights; sw becomes act buffer
#pragma unroll
    for (int oo = 0; oo < 6; ++oo) {
        float4 st = make_float4(lk(acc[0][oo]), lk(acc[1][oo]), lk(acc[2][oo]), lk(acc[3][oo]));
        *(float4*)&sw[(obase + oo) * 256 + 4 * L] = st;
    }
    __syncthreads();

    float acc2[CO];
#pragma unroll
    for (int o = 0; o < CO; ++o) acc2[o] = sbr[o];
    for (int c = 0; c < CO; ++c) {
        const float in_c = sw[c * 256 + t];
#pragma unroll
        for (int m = 0; m < 6; ++m) {
            const float4 wv = *(const float4*)&swt[c * CO + 4 * m];   // 16B aligned
            acc2[4 * m + 0] = fmaf(in_c, wv.x, acc2[4 * m + 0]);
            acc2[4 * m + 1] = fmaf(in_c, wv.y, acc2[4 * m + 1]);
            acc2[4 * m + 2] = fmaf(in_c, wv.z, acc2[4 * m + 2]);
            acc2[4 * m + 3] = fmaf(in_c, wv.w, acc2[4 * m + 3]);
        }
    }
#pragma unroll
    for (int o = 0; o < CO; ++o)
        out[((size_t)(b * CO + o) * HQ + h) * WR + jbase + t] = lk(acc2[o]);
}

// ====== Kernel C: cost volume + min/argmin + tf 1x1 + output assembly ========
// block 256 = 64 j-lanes x 4 waves (wave w owns d in [16w,16w+16)); grid 960.
// LDS layout: frs[c*324 + 2 + (col - colbase)], colbase = 4*j0-64; cols<0
// replicated with fr[c][0] (reference's lower clip; upper clip never fires).
// The +2 shift makes each (c, d-quad) gather group of 4 consecutive cols
// 16B-aligned -> one ds_read_b128 replaces 4 ds_read_b32. Channel-ascending
// += of fabsf keeps costs bitwise-identical -> argmin tie behavior preserved.
__global__ __launch_bounds__(256) void k_cost(
    const float* __restrict__ fl, const float* __restrict__ fr,
    const float* __restrict__ wtf, const float* __restrict__ btf,
    float* __restrict__ out, float* __restrict__ cost)
{
    __shared__ float frs[CO * 324];       // 31104 B
    __shared__ float sbest[256];
    __shared__ int   sbd[256];

    const int t  = threadIdx.x;
    const int j  = t & 63;                 // lane = local col
    const int w  = t >> 6;                 // wave: d in [16w, 16w+16)
    const int jc = blockIdx.x % 5;
    const int r  = blockIdx.x / 5;
    const int h  = r % HQ, b = r / HQ;
    const int j0 = jc * 64;
    const int jg = j0 + j;
    const int colbase = 4 * j0 - 64;

    // stage 24 rows x 320 cols (coalesced; left-clip replication)
    for (int idx = t; idx < CO * 320; idx += 256) {
        const int c = idx / 320, Wd = idx % 320;
        const int col = colbase + Wd;
        frs[c * 324 + 2 + Wd] = fr[((size_t)(b * CO + c) * HQ + h) * WR + (col > 0 ? col : 0)];
    }
    __syncthreads();

    float acc[4][4];                       // [q][r], d = 16w + 4q + r
#pragma unroll
    for (int q = 0; q < 4; ++q)
#pragma unroll
        for (int rr = 0; rr < 4; ++rr) acc[q][rr] = 0.f;

    for (int c = 0; c < CO; ++c) {
        const float flc = fl[((size_t)(b * CO + c) * HQ + h) * WL + jg];
        const float* base = &frs[c * 324 + 4 * j + 64];
#pragma unroll
        for (int q = 0; q < 4; ++q) {
            const int D = 4 * w + q;
            const float4 v = *(const float4*)(base - 4 * D);  // 16B-aligned
            acc[q][0] += fabsf(flc - v.w);   // d = 4D
            acc[q][1] += fabsf(flc - v.z);   // d = 4D+1
            acc[q][2] += fabsf(flc - v.y);   // d = 4D+2
            acc[q][3] += fabsf(flc - v.x);   // d = 4D+3
        }
    }

    // cost volume writes (coalesced over jg)
#pragma unroll
    for (int q = 0; q < 4; ++q)
#pragma unroll
        for (int rr = 0; rr < 4; ++rr) {
            const int d = 16 * w + 4 * q + rr;
            cost[((size_t)(b * DMAX + d) * HQ + h) * WL + jg] = acc[q][rr];
        }

    // per-thread min / first-occurrence argmin (ascending d within wave range)
    float best = acc[0][0]; int bd = 16 * w;
#pragma unroll
    for (int q = 0; q < 4; ++q)
#pragma unroll
        for (int rr = 0; rr < 4; ++rr) {
            if (q == 0 && rr == 0) continue;
            const int d = 16 * w + 4 * q + rr;
            if (acc[q][rr] < best) { best = acc[q][rr]; bd = d; }
        }
    sbest[t] = best; sbd[t] = bd;
    __syncthreads();

    if (t < 64) {
        float cur = sbest[j]; int curd = sbd[j];
#pragma unroll
        for (int g = 1; g < 4; ++g) {
            const float v = sbest[g * 64 + j];
            if (v < cur) { cur = v; curd = sbd[g * 64 + j]; }
        }
        float flr[CO];
#pragma unroll
        for (int c = 0; c < CO; ++c) flr[c] = fl[((size_t)(b * CO + c) * HQ + h) * WL + jg];
#pragma unroll
        for (int o = 0; o < 13; ++o) {
            float a = btf[o] + wtf[o * 25] * cur;
#pragma unroll
            for (int c = 0; c < CO; ++c) a += wtf[o * 25 + 1 + c] * flr[c];
            out[((size_t)(b * 16 + 3 + o) * HQ + h) * WL + jg] = lk(a);
        }
        out[((size_t)(b * 16 + 0) * HQ + h) * WL + jg] = (float)curd;
        out[((size_t)(b * 16 + 1) * HQ + h) * WL + jg] = 0.f;
        out[((size_t)(b * 16 + 2) * HQ + h) * WL + jg] = 0.f;
    }
}

extern "C" void kernel_launch(void* const* d_in, const int* in_sizes, int n_in,
                              void* d_out, int out_size, void* d_ws, size_t ws_size,
                              hipStream_t stream) {
    const float* fl_in = (const float*)d_in[0];
    const float* fr_in = (const float*)d_in[1];
    // d_in[2] = max_disp (int) -- fixed 64
    const float* w_em = (const float*)d_in[3];
    const float* b_em = (const float*)d_in[4];
    const float* w_rc = (const float*)d_in[5];
    const float* b_rc = (const float*)d_in[6];
    const float* w_tf = (const float*)d_in[7];
    const float* b_tf = (const float*)d_in[8];

    float* out  = (float*)d_out;
    float* cost = out + (size_t)B_ * 16 * HQ * WL;

    float* fl_ws = (float*)d_ws;                               // [2,24,96,320]
    float* fr_ws = fl_ws + (size_t)B_ * CO * HQ * WL;          // [2,24,96,1280]

    hipLaunchKernelGGL(k_right, dim3(960), dim3(256), 0, stream,
                       fr_in, w_em, b_em, w_rc, b_rc, fr_ws);
    hipLaunchKernelGGL(k_left,  dim3(480), dim3(256), 0, stream,
                       fl_in, w_em, b_em, w_rc, b_rc, fl_ws);
    hipLaunchKernelGGL(k_cost,  dim3(960), dim3(256), 0, stream,
                       fl_ws, fr_ws, w_tf, b_tf, out, cost);
}